// Round 3
// baseline (357.557 us; speedup 1.0000x reference)
//
#include <hip/hip_runtime.h>

constexpr int NB = 10, H = 128;
constexpr int M = 64 * 1024;             // B*A rows
constexpr long SL = (long)M * H;         // elems per [M,H] matrix

typedef __attribute__((ext_vector_type(8))) short s16x8;
typedef __attribute__((ext_vector_type(4))) float f32x4;

__device__ __forceinline__ ushort f2b(float f) {
    union { float f; uint u; } v; v.f = f;
    uint u = v.u;
    uint r = u + 0x7fffu + ((u >> 16) & 1u);
    return (ushort)(r >> 16);
}
__device__ __forceinline__ float b2f(ushort u) {
    union { uint u; float f; } v; v.u = ((uint)u) << 16; return v.f;
}

// XCD-chunked bijective swizzle (grid % 8 == 0): XCD r gets contiguous chunk
__device__ __forceinline__ int swz(int bid, int cpx) {
    return (bid & 7) * cpx + (bid >> 3);
}

// ---------------------------------------------------------------------------
// MFMA row-GEMM (exact grid: 1024 blocks, 4 waves, 1 16-row tile per wave).
// C[M][128] = A[M][K=NC*32](bf16) @ W[K][128];  WT = W^T [128][K] bf16.
// FLAGS: 1=FBS (+FBS8@W2 via padded K=32 chunk), 8=KOUT (v*=b2f(FN)*nmask),
//        16=OUTF32
// ---------------------------------------------------------------------------
template<int NC, int FLAGS>
__global__ __launch_bounds__(256, 2) void gemm_mf(
    const ushort* __restrict__ Abf, const ushort* __restrict__ WT,
    const ushort* __restrict__ FBSb, const ushort* __restrict__ WT2,
    const ushort* __restrict__ FNb, const float* __restrict__ nmask,
    float* __restrict__ Cf, ushort* __restrict__ Cb)
{
    constexpr bool FBS = FLAGS & 1, KOUT = FLAGS & 8, OF32 = FLAGS & 16;
    constexpr int K = NC * 32;
    const int lane = threadIdx.x & 63, wid = threadIdx.x >> 6;
    const int l15 = lane & 15, g = lane >> 4;
    const int bid = swz(blockIdx.x, 128);
    const int m0 = (bid * 4 + wid) * 16;

    s16x8 bfr[8][NC];
    #pragma unroll
    for (int c = 0; c < 8; ++c)
        #pragma unroll
        for (int kc = 0; kc < NC; ++kc)
            bfr[c][kc] = *(const s16x8*)(WT + (size_t)(c * 16 + l15) * K + kc * 32 + g * 8);

    s16x8 afr[NC];
    #pragma unroll
    for (int kc = 0; kc < NC; ++kc)
        afr[kc] = *(const s16x8*)(Abf + (size_t)(m0 + l15) * K + kc * 32 + g * 8);

    f32x4 acc[8];
    #pragma unroll
    for (int c = 0; c < 8; ++c) acc[c] = (f32x4){0.f, 0.f, 0.f, 0.f};
    #pragma unroll
    for (int kc = 0; kc < NC; ++kc)
        #pragma unroll
        for (int c = 0; c < 8; ++c)
            acc[c] = __builtin_amdgcn_mfma_f32_16x16x32_bf16(afr[kc], bfr[c][kc], acc[c], 0, 0, 0);

    if constexpr (FBS) {
        s16x8 af2 = (s16x8){0,0,0,0,0,0,0,0};
        if (g == 0) af2 = *(const s16x8*)(FBSb + (size_t)(m0 + l15) * 8);
        #pragma unroll
        for (int c = 0; c < 8; ++c) {
            s16x8 b2 = *(const s16x8*)(WT2 + (size_t)(c * 16 + l15) * 32 + g * 8);
            acc[c] = __builtin_amdgcn_mfma_f32_16x16x32_bf16(af2, b2, acc[c], 0, 0, 0);
        }
    }

    #pragma unroll
    for (int c = 0; c < 8; ++c) {
        const int col = c * 16 + l15;
        #pragma unroll
        for (int r = 0; r < 4; ++r) {
            const int m = m0 + 4 * g + r;
            const size_t o = (size_t)m * H + col;
            float v = acc[c][r];
            if constexpr (KOUT) v = v * b2f(FNb[o]) * nmask[m];
            if constexpr (OF32) Cf[o] = v; else Cb[o] = f2b(v);
        }
    }
}

// ---------------------------------------------------------------------------
// K1: fused neighbor-gather + U2 GEMM (depths 0,1).
// SATOM accumulated directly into MFMA A-frags (branch-free masked over NB).
// NLBL = SATOM @ W_U2a + FBS8 @ W2  -> bf16
// ---------------------------------------------------------------------------
__global__ __launch_bounds__(256, 2) void k1_gather_u2(
    const ushort* __restrict__ AF, const ushort* __restrict__ FBSb,
    const ushort* __restrict__ WTu2a, const ushort* __restrict__ WT2p,
    const int* __restrict__ ag, const int* __restrict__ nn,
    ushort* __restrict__ NLBL)
{
    const int lane = threadIdx.x & 63, wid = threadIdx.x >> 6;
    const int l15 = lane & 15, g = lane >> 4;
    const int bid = swz(blockIdx.x, 128);
    const int m0 = (bid * 4 + wid) * 16;
    const int row = m0 + l15;
    const int b = row >> 10;
    const ushort* AFb = AF + ((size_t)b << 10) * H + g * 8;

    s16x8 bfr[8][4];
    #pragma unroll
    for (int c = 0; c < 8; ++c)
        #pragma unroll
        for (int kc = 0; kc < 4; ++kc)
            bfr[c][kc] = *(const s16x8*)(WTu2a + (size_t)(c * 16 + l15) * 128 + kc * 32 + g * 8);

    const int nnb = nn[row];
    int2 iv[5];
    #pragma unroll
    for (int p = 0; p < 5; ++p)
        iv[p] = *(const int2*)(ag + (size_t)row * NB + 2 * p);

    float sacc[4][8];
    #pragma unroll
    for (int kc = 0; kc < 4; ++kc)
        #pragma unroll
        for (int j = 0; j < 8; ++j) sacc[kc][j] = 0.f;

    #pragma unroll
    for (int p = 0; p < 5; ++p) {
        #pragma unroll
        for (int hh = 0; hh < 2; ++hh) {
            const int nb = 2 * p + hh;
            const float w = (nb < nnb) ? 1.f : 0.f;
            const int ia = hh ? iv[p].y : iv[p].x;
            const ushort* src = AFb + (size_t)ia * H;
            #pragma unroll
            for (int kc = 0; kc < 4; ++kc) {
                s16x8 v = *(const s16x8*)(src + kc * 32);
                #pragma unroll
                for (int j = 0; j < 8; ++j)
                    sacc[kc][j] += w * b2f((ushort)v[j]);
            }
        }
    }

    s16x8 afr[4];
    #pragma unroll
    for (int kc = 0; kc < 4; ++kc)
        #pragma unroll
        for (int j = 0; j < 8; ++j) afr[kc][j] = (short)f2b(sacc[kc][j]);

    f32x4 acc[8];
    #pragma unroll
    for (int c = 0; c < 8; ++c) acc[c] = (f32x4){0.f, 0.f, 0.f, 0.f};
    #pragma unroll
    for (int kc = 0; kc < 4; ++kc)
        #pragma unroll
        for (int c = 0; c < 8; ++c)
            acc[c] = __builtin_amdgcn_mfma_f32_16x16x32_bf16(afr[kc], bfr[c][kc], acc[c], 0, 0, 0);

    s16x8 af2 = (s16x8){0,0,0,0,0,0,0,0};
    if (g == 0) af2 = *(const s16x8*)(FBSb + (size_t)row * 8);
    #pragma unroll
    for (int c = 0; c < 8; ++c) {
        s16x8 b2 = *(const s16x8*)(WT2p + (size_t)(c * 16 + l15) * 32 + g * 8);
        acc[c] = __builtin_amdgcn_mfma_f32_16x16x32_bf16(af2, b2, acc[c], 0, 0, 0);
    }

    #pragma unroll
    for (int c = 0; c < 8; ++c) {
        const int col = c * 16 + l15;
        #pragma unroll
        for (int r = 0; r < 4; ++r)
            NLBL[(size_t)(m0 + 4 * g + r) * H + col] = f2b(acc[c][r]);
    }
}

// ---------------------------------------------------------------------------
// K2: fused U1, K=256:  AFn = [AF | NLBL] @ W_U1 + b_U1
// 2 waves per 16-row tile (4 coltiles each); exact grid 2048 blocks.
// ---------------------------------------------------------------------------
template<bool OF32>
__global__ __launch_bounds__(256, 2) void k2_u1(
    const ushort* __restrict__ AF, const ushort* __restrict__ NLBL,
    const ushort* __restrict__ WTu1s, const float* __restrict__ bias,
    float* __restrict__ Cf, ushort* __restrict__ Cb)
{
    const int lane = threadIdx.x & 63, wid = threadIdx.x >> 6;
    const int l15 = lane & 15, g = lane >> 4;
    const int t  = blockIdx.x * 2 + (wid >> 1);
    const int c0 = (wid & 1) * 4;
    const int m0 = t * 16;

    s16x8 bfr[4][8];
    #pragma unroll
    for (int ci = 0; ci < 4; ++ci)
        #pragma unroll
        for (int kc = 0; kc < 8; ++kc)
            bfr[ci][kc] = *(const s16x8*)(WTu1s + (size_t)((c0 + ci) * 16 + l15) * 256 + kc * 32 + g * 8);

    s16x8 afr[8];
    #pragma unroll
    for (int kc = 0; kc < 4; ++kc) {
        afr[kc]     = *(const s16x8*)(AF   + (size_t)(m0 + l15) * H + kc * 32 + g * 8);
        afr[kc + 4] = *(const s16x8*)(NLBL + (size_t)(m0 + l15) * H + kc * 32 + g * 8);
    }

    f32x4 acc[4];
    #pragma unroll
    for (int ci = 0; ci < 4; ++ci) acc[ci] = (f32x4){0.f, 0.f, 0.f, 0.f};
    #pragma unroll
    for (int kc = 0; kc < 8; ++kc)
        #pragma unroll
        for (int ci = 0; ci < 4; ++ci)
            acc[ci] = __builtin_amdgcn_mfma_f32_16x16x32_bf16(afr[kc], bfr[ci][kc], acc[ci], 0, 0, 0);

    #pragma unroll
    for (int ci = 0; ci < 4; ++ci) {
        const int col = (c0 + ci) * 16 + l15;
        const float bc = bias[col];
        #pragma unroll
        for (int r = 0; r < 4; ++r) {
            const size_t o = (size_t)(m0 + 4 * g + r) * H + col;
            const float v = acc[ci][r] + bc;
            if constexpr (OF32) Cf[o] = v; else Cb[o] = f2b(v);
        }
    }
}

// ---------------------------------------------------------------------------
// Last-depth gather: SATOM (bf16) and FNEI (bf16) with vector idx loads and
// branch-free masked accumulation. 16 threads/row, 8 cols each.
// ---------------------------------------------------------------------------
__global__ __launch_bounds__(256) void gather_last(
    const ushort* __restrict__ AF, const ushort* __restrict__ ATW,
    const float* __restrict__ bond, const int* __restrict__ ag,
    const int* __restrict__ bg, const int* __restrict__ nn,
    const float* __restrict__ Wnb, ushort* __restrict__ SATOM,
    ushort* __restrict__ FNEIb)
{
    const int bid = swz(blockIdx.x, 512);
    const int m  = bid * 16 + (threadIdx.x >> 4);
    const int c8 = (threadIdx.x & 15) * 8;
    const int b  = m >> 10;
    const int nnb = nn[m];

    float WnbR[6][8];
    #pragma unroll
    for (int j = 0; j < 6; ++j)
        #pragma unroll
        for (int i = 0; i < 8; ++i) WnbR[j][i] = Wnb[j * H + c8 + i];

    int2 iva[5], ivb[5];
    #pragma unroll
    for (int p = 0; p < 5; ++p) {
        iva[p] = *(const int2*)(ag + (size_t)m * NB + 2 * p);
        ivb[p] = *(const int2*)(bg + (size_t)m * NB + 2 * p);
    }

    float sacc[8], facc[8];
    #pragma unroll
    for (int i = 0; i < 8; ++i) { sacc[i] = 0.f; facc[i] = 0.f; }

    const ushort* AFb  = AF  + ((size_t)b << 10) * H + c8;
    const ushort* ATWb = ATW + ((size_t)b << 10) * H + c8;
    const float*  bb   = bond + ((size_t)b << 11) * 6;

    #pragma unroll
    for (int p = 0; p < 5; ++p) {
        #pragma unroll
        for (int hh = 0; hh < 2; ++hh) {
            const int nb = 2 * p + hh;
            const float w = (nb < nnb) ? 1.f : 0.f;
            const int ia = hh ? iva[p].y : iva[p].x;
            const int ib = hh ? ivb[p].y : ivb[p].x;
            s16x8 av = *(const s16x8*)(AFb  + (size_t)ia * H);
            s16x8 tv = *(const s16x8*)(ATWb + (size_t)ia * H);
            const float* fb = bb + (size_t)ib * 6;
            const float2 f01 = *(const float2*)fb;
            const float2 f23 = *(const float2*)(fb + 2);
            const float2 f45 = *(const float2*)(fb + 4);
            #pragma unroll
            for (int i = 0; i < 8; ++i) {
                const float hnb = f01.x * WnbR[0][i] + f01.y * WnbR[1][i]
                                + f23.x * WnbR[2][i] + f23.y * WnbR[3][i]
                                + f45.x * WnbR[4][i] + f45.y * WnbR[5][i];
                sacc[i] += w * b2f((ushort)av[i]);
                facc[i] += (w * hnb) * b2f((ushort)tv[i]);
            }
        }
    }

    s16x8 so, fo;
    #pragma unroll
    for (int i = 0; i < 8; ++i) { so[i] = (short)f2b(sacc[i]); fo[i] = (short)f2b(facc[i]); }
    *(s16x8*)(SATOM + (size_t)m * H + c8) = so;
    *(s16x8*)(FNEIb + (size_t)m * H + c8) = fo;
}

// FBS8[m][8] = bf16[ sum_nb bond[bg[m,nb]][0..5], num_nbs, 0 ]
__global__ __launch_bounds__(256) void prep_fbs(
    const float* __restrict__ bond, const int* __restrict__ bg,
    const int* __restrict__ nn, ushort* __restrict__ FBSb)
{
    const int m = blockIdx.x * 256 + threadIdx.x;
    const int b = m >> 10;
    const int nnb = nn[m];
    float s[6] = {0,0,0,0,0,0};
    for (int nb = 0; nb < nnb; ++nb) {
        const int ib = bg[m * NB + nb];
        const float* fb = bond + ((size_t)(b << 11) + (size_t)ib) * 6;
        #pragma unroll
        for (int j = 0; j < 6; ++j) s[j] += fb[j];
    }
    s16x8 o;
    #pragma unroll
    for (int j = 0; j < 6; ++j) o[j] = (short)f2b(s[j]);
    o[6] = (short)f2b((float)nnb);
    o[7] = 0;
    *(s16x8*)(FBSb + (size_t)m * 8) = o;
}

// input_atom [M][82] f32 -> [M][96] bf16 (zero-padded)
__global__ __launch_bounds__(256) void cvt_atom(
    const float* __restrict__ ia, ushort* __restrict__ out)
{
    const int tid = blockIdx.x * 256 + threadIdx.x;   // M*12
    const int m = tid / 12, c = (tid % 12) * 8;
    s16x8 v;
    #pragma unroll
    for (int i = 0; i < 8; ++i) {
        const int k = c + i;
        v[i] = (short)(k < 82 ? f2b(ia[(size_t)m * 82 + k]) : 0);
    }
    *(s16x8*)(out + (size_t)m * 96 + c) = v;
}

// Transposed bf16 weights:
// WTa[128][96] | WTna[128][128] | WTslf[128][128] | WTu2a[128][128]
// | WTu1s[128][256] | WT2p[128][32]   (total 98304 elems)
__global__ __launch_bounds__(256) void prep_w(
    const float* __restrict__ Wa, const float* __restrict__ Wna,
    const float* __restrict__ Ws, const float* __restrict__ Wu2,
    const float* __restrict__ bu2, const float* __restrict__ Wu1,
    ushort* __restrict__ out)
{
    int t = blockIdx.x * 256 + threadIdx.x;
    const int tid = t;
    if (t < 128 * 96) { int n = t / 96, k = t % 96;
        out[tid] = (k < 82) ? f2b(Wa[k * H + n]) : 0; return; }
    t -= 128 * 96;
    if (t < 128 * 128) { int n = t / 128, k = t % 128;
        out[tid] = f2b(Wna[k * H + n]); return; }
    t -= 128 * 128;
    if (t < 128 * 128) { int n = t / 128, k = t % 128;
        out[tid] = f2b(Ws[k * H + n]); return; }
    t -= 128 * 128;
    if (t < 128 * 128) { int n = t / 128, k = t % 128;
        out[tid] = f2b(Wu2[k * H + n]); return; }
    t -= 128 * 128;
    if (t < 128 * 256) { int n = t / 256, k = t % 256;
        out[tid] = f2b(Wu1[k * H + n]); return; }
    t -= 128 * 256;
    if (t < 128 * 32) { int n = t / 32, j = t % 32;
        ushort v = 0;
        if (j < 6) v = f2b(Wu2[(128 + j) * H + n]);
        else if (j == 6) v = f2b(bu2[n]);
        out[tid] = v; return; }
}

// ---------------------------------------------------------------------------
extern "C" void kernel_launch(void* const* d_in, const int* in_sizes, int n_in,
                              void* d_out, int out_size, void* d_ws, size_t ws_size,
                              hipStream_t stream)
{
    (void)in_sizes; (void)n_in; (void)out_size; (void)ws_size;

    const float* input_atom = (const float*)d_in[0];
    const float* input_bond = (const float*)d_in[1];
    const int*   atom_graph = (const int*)d_in[2];
    const int*   bond_graph = (const int*)d_in[3];
    const int*   num_nbs    = (const int*)d_in[4];
    const float* node_mask  = (const float*)d_in[5];
    const float* W_atom     = (const float*)d_in[6];
    const float* W_nei_atom = (const float*)d_in[7];
    const float* W_nei_bond = (const float*)d_in[8];
    const float* W_self     = (const float*)d_in[9];
    const float* W_U2       = (const float*)d_in[10];
    const float* b_U2       = (const float*)d_in[11];
    const float* W_U1       = (const float*)d_in[12];
    const float* b_U1       = (const float*)d_in[13];

    char* ws = (char*)d_ws;
    ushort* AF0   = (ushort*)(ws);               // 16 MB
    ushort* AF1   = (ushort*)(ws + SL * 2);      // 16 MB
    ushort* NLBL  = (ushort*)(ws + SL * 4);      // 16 MB
    ushort* ATW   = (ushort*)(ws + SL * 6);      // 16 MB (last depth)
    ushort* AFin  = (ushort*)(ws + SL * 8);      // 12 MB (dead after FA gemm)
    ushort* FNEIb = (ushort*)(ws + SL * 8);      // 16 MB (written much later)
    ushort* FBSb  = (ushort*)(ws + SL * 10);     // 1 MB
    ushort* WTs_  = (ushort*)(ws + SL * 10 + (size_t)M * 8 * 2);

    ushort* WTa   = WTs_;                        // [128][96]
    ushort* WTna  = WTa   + 128 * 96;            // [128][128]
    ushort* WTslf = WTna  + 128 * 128;
    ushort* WTu2a = WTslf + 128 * 128;
    ushort* WTu1s = WTu2a + 128 * 128;           // [128][256]
    ushort* WT2p  = WTu1s + 128 * 256;           // [128][32]

    float*  out0  = (float*)d_out;               // kernel [M][128] f32
    float*  out1  = out0 + SL;                   // atom_features [M][128] f32
    ushort* SATOM = (ushort*)out0;               // scratch bf16 (pre-KOUT)

    prep_w<<<384, 256, 0, stream>>>(W_atom, W_nei_atom, W_self, W_U2, b_U2, W_U1, WTs_);
    cvt_atom<<<3072, 256, 0, stream>>>(input_atom, AFin);
    prep_fbs<<<256, 256, 0, stream>>>(input_bond, bond_graph, num_nbs, FBSb);

    // AF0 = input_atom @ W_atom   (K=96 padded)
    gemm_mf<3, 0><<<1024, 256, 0, stream>>>(AFin, WTa, nullptr, nullptr,
                                            nullptr, nullptr, nullptr, AF0);

    ushort* AF  = AF0;
    ushort* AFn = AF1;
    for (int d = 0; d < 2; ++d) {
        k1_gather_u2<<<1024, 256, 0, stream>>>(AF, FBSb, WTu2a, WT2p,
                                               atom_graph, num_nbs, NLBL);
        k2_u1<false><<<2048, 256, 0, stream>>>(AF, NLBL, WTu1s, b_U1, nullptr, AFn);
        ushort* t = AF; AF = AFn; AFn = t;
    }

    // ---- last depth ----
    gemm_mf<4, 0><<<1024, 256, 0, stream>>>(AF, WTna, nullptr, nullptr,
                                            nullptr, nullptr, nullptr, ATW);
    gather_last<<<4096, 256, 0, stream>>>(AF, ATW, input_bond, atom_graph,
                                          bond_graph, num_nbs, W_nei_bond,
                                          SATOM, FNEIb);
    gemm_mf<4, 1><<<1024, 256, 0, stream>>>(SATOM, WTu2a, FBSb, WT2p,
                                            nullptr, nullptr, nullptr, NLBL);
    // atom_features -> out1 (f32)
    k2_u1<true><<<2048, 256, 0, stream>>>(AF, NLBL, WTu1s, b_U1, out1, nullptr);
    // kernel = (AF @ W_self) * FNEI * node_mask -> out0 (f32)
    gemm_mf<4, 8 | 16><<<1024, 256, 0, stream>>>(AF, WTslf, nullptr, nullptr,
                                                 FNEIb, node_mask, out0, nullptr);
}

// Round 4
// 343.527 us; speedup vs baseline: 1.0408x; 1.0408x over previous
//
#include <hip/hip_runtime.h>

constexpr int NB = 10, H = 128;
constexpr int M = 64 * 1024;             // B*A rows
constexpr long SL = (long)M * H;         // elems per [M,H] matrix

typedef __attribute__((ext_vector_type(8))) short s16x8;
typedef __attribute__((ext_vector_type(4))) float f32x4;

__device__ __forceinline__ ushort f2b(float f) {
    union { float f; uint u; } v; v.f = f;
    uint u = v.u;
    uint r = u + 0x7fffu + ((u >> 16) & 1u);
    return (ushort)(r >> 16);
}
__device__ __forceinline__ float b2f(ushort u) {
    union { uint u; float f; } v; v.u = ((uint)u) << 16; return v.f;
}

// XCD-chunked bijective swizzle (grid % 8 == 0)
__device__ __forceinline__ int swz(int bid, int cpx) {
    return (bid & 7) * cpx + (bid >> 3);
}

// ---------------------------------------------------------------------------
// MFMA row-GEMM (exact grid: 1024 blocks, 4 waves, one 16-row tile per wave).
// C[M][128] = A[M][K=NC*32](bf16) @ W[K][128];  WT = W^T [128][K] bf16.
// FLAGS: 1=FBS (+FBS8@W2 via padded K=32 chunk), 8=KOUT (v*=b2f(FN)*nmask),
//        16=OUTF32
// ---------------------------------------------------------------------------
template<int NC, int FLAGS>
__global__ __launch_bounds__(256, 2) void gemm_mf(
    const ushort* __restrict__ Abf, const ushort* __restrict__ WT,
    const ushort* __restrict__ FBSb, const ushort* __restrict__ WT2,
    const ushort* __restrict__ FNb, const float* __restrict__ nmask,
    float* __restrict__ Cf, ushort* __restrict__ Cb)
{
    constexpr bool FBS = FLAGS & 1, KOUT = FLAGS & 8, OF32 = FLAGS & 16;
    constexpr int K = NC * 32;
    const int lane = threadIdx.x & 63, wid = threadIdx.x >> 6;
    const int l15 = lane & 15, g = lane >> 4;
    const int bid = swz(blockIdx.x, 128);
    const int m0 = (bid * 4 + wid) * 16;

    s16x8 bfr[8][NC];
    #pragma unroll
    for (int c = 0; c < 8; ++c)
        #pragma unroll
        for (int kc = 0; kc < NC; ++kc)
            bfr[c][kc] = *(const s16x8*)(WT + (size_t)(c * 16 + l15) * K + kc * 32 + g * 8);

    s16x8 afr[NC];
    #pragma unroll
    for (int kc = 0; kc < NC; ++kc)
        afr[kc] = *(const s16x8*)(Abf + (size_t)(m0 + l15) * K + kc * 32 + g * 8);

    f32x4 acc[8];
    #pragma unroll
    for (int c = 0; c < 8; ++c) acc[c] = (f32x4){0.f, 0.f, 0.f, 0.f};
    #pragma unroll
    for (int kc = 0; kc < NC; ++kc)
        #pragma unroll
        for (int c = 0; c < 8; ++c)
            acc[c] = __builtin_amdgcn_mfma_f32_16x16x32_bf16(afr[kc], bfr[c][kc], acc[c], 0, 0, 0);

    if constexpr (FBS) {
        s16x8 af2 = (s16x8){0,0,0,0,0,0,0,0};
        if (g == 0) af2 = *(const s16x8*)(FBSb + (size_t)(m0 + l15) * 8);
        #pragma unroll
        for (int c = 0; c < 8; ++c) {
            s16x8 b2 = *(const s16x8*)(WT2 + (size_t)(c * 16 + l15) * 32 + g * 8);
            acc[c] = __builtin_amdgcn_mfma_f32_16x16x32_bf16(af2, b2, acc[c], 0, 0, 0);
        }
    }

    #pragma unroll
    for (int c = 0; c < 8; ++c) {
        const int col = c * 16 + l15;
        #pragma unroll
        for (int r = 0; r < 4; ++r) {
            const int m = m0 + 4 * g + r;
            const size_t o = (size_t)m * H + col;
            float v = acc[c][r];
            if constexpr (KOUT) v = v * b2f(FNb[o]) * nmask[m];
            if constexpr (OF32) Cf[o] = v; else Cb[o] = f2b(v);
        }
    }
}

// ---------------------------------------------------------------------------
// K2: fused U1, K=256:  AFn = [AF | NLBL] @ W_U1 + b_U1
// ---------------------------------------------------------------------------
template<bool OF32>
__global__ __launch_bounds__(256, 2) void k2_u1(
    const ushort* __restrict__ AF, const ushort* __restrict__ NLBL,
    const ushort* __restrict__ WTu1s, const float* __restrict__ bias,
    float* __restrict__ Cf, ushort* __restrict__ Cb)
{
    const int lane = threadIdx.x & 63, wid = threadIdx.x >> 6;
    const int l15 = lane & 15, g = lane >> 4;
    const int t  = blockIdx.x * 2 + (wid >> 1);
    const int c0 = (wid & 1) * 4;
    const int m0 = t * 16;

    s16x8 bfr[4][8];
    #pragma unroll
    for (int ci = 0; ci < 4; ++ci)
        #pragma unroll
        for (int kc = 0; kc < 8; ++kc)
            bfr[ci][kc] = *(const s16x8*)(WTu1s + (size_t)((c0 + ci) * 16 + l15) * 256 + kc * 32 + g * 8);

    s16x8 afr[8];
    #pragma unroll
    for (int kc = 0; kc < 4; ++kc) {
        afr[kc]     = *(const s16x8*)(AF   + (size_t)(m0 + l15) * H + kc * 32 + g * 8);
        afr[kc + 4] = *(const s16x8*)(NLBL + (size_t)(m0 + l15) * H + kc * 32 + g * 8);
    }

    f32x4 acc[4];
    #pragma unroll
    for (int ci = 0; ci < 4; ++ci) acc[ci] = (f32x4){0.f, 0.f, 0.f, 0.f};
    #pragma unroll
    for (int kc = 0; kc < 8; ++kc)
        #pragma unroll
        for (int ci = 0; ci < 4; ++ci)
            acc[ci] = __builtin_amdgcn_mfma_f32_16x16x32_bf16(afr[kc], bfr[ci][kc], acc[ci], 0, 0, 0);

    #pragma unroll
    for (int ci = 0; ci < 4; ++ci) {
        const int col = (c0 + ci) * 16 + l15;
        const float bc = bias[col];
        #pragma unroll
        for (int r = 0; r < 4; ++r) {
            const size_t o = (size_t)(m0 + 4 * g + r) * H + col;
            const float v = acc[ci][r] + bc;
            if constexpr (OF32) Cf[o] = v; else Cb[o] = f2b(v);
        }
    }
}

// ---------------------------------------------------------------------------
// SATOM gather only: SATOM[m][:] = sum_{nb<nnb} AF[b, ag[m,nb]][:]  (bf16)
// 16 threads/row, 8 cols each; masked-unconditional loads for ILP; low VGPR.
// ---------------------------------------------------------------------------
__global__ __launch_bounds__(256, 6) void gather_satom(
    const ushort* __restrict__ AF, const int* __restrict__ ag,
    const int* __restrict__ nn, ushort* __restrict__ SATOM)
{
    const int bid = swz(blockIdx.x, 512);
    const int m  = bid * 16 + (threadIdx.x >> 4);
    const int c8 = (threadIdx.x & 15) * 8;
    const int b  = m >> 10;
    const int nnb = nn[m];
    const ushort* AFb = AF + ((size_t)b << 10) * H + c8;
    const int* agm = ag + (size_t)m * NB;

    int2 iv0 = *(const int2*)(agm + 0);
    int2 iv1 = *(const int2*)(agm + 2);
    int2 iv2 = *(const int2*)(agm + 4);
    int2 iv3 = *(const int2*)(agm + 6);
    int2 iv4 = *(const int2*)(agm + 8);

    float sacc[8];
    #pragma unroll
    for (int i = 0; i < 8; ++i) sacc[i] = 0.f;

    #define GS_STEP(nb, ia)                                              \
    {                                                                    \
        const float w = ((nb) < nnb) ? 1.f : 0.f;                        \
        s16x8 av = *(const s16x8*)(AFb + (size_t)(ia) * H);              \
        _Pragma("unroll")                                                \
        for (int i = 0; i < 8; ++i) sacc[i] += w * b2f((ushort)av[i]);   \
    }
    GS_STEP(0, iv0.x) GS_STEP(1, iv0.y)
    GS_STEP(2, iv1.x) GS_STEP(3, iv1.y)
    GS_STEP(4, iv2.x) GS_STEP(5, iv2.y)
    GS_STEP(6, iv3.x) GS_STEP(7, iv3.y)
    GS_STEP(8, iv4.x) GS_STEP(9, iv4.y)
    #undef GS_STEP

    s16x8 so;
    #pragma unroll
    for (int i = 0; i < 8; ++i) so[i] = (short)f2b(sacc[i]);
    *(s16x8*)(SATOM + (size_t)m * H + c8) = so;
}

// ---------------------------------------------------------------------------
// Last-depth gather: SATOM and FNEI = sum_nb ATW[ag]*HB[bg]  (both bf16 out)
// HB precomputed -> no per-thread weight cache; ~60 VGPR.
// ---------------------------------------------------------------------------
__global__ __launch_bounds__(256, 4) void gather_last(
    const ushort* __restrict__ AF, const ushort* __restrict__ ATW,
    const ushort* __restrict__ HB, const int* __restrict__ ag,
    const int* __restrict__ bg, const int* __restrict__ nn,
    ushort* __restrict__ SATOM, ushort* __restrict__ FNEIb)
{
    const int bid = swz(blockIdx.x, 512);
    const int m  = bid * 16 + (threadIdx.x >> 4);
    const int c8 = (threadIdx.x & 15) * 8;
    const int b  = m >> 10;
    const int nnb = nn[m];
    const ushort* AFb  = AF  + ((size_t)b << 10) * H + c8;
    const ushort* ATWb = ATW + ((size_t)b << 10) * H + c8;
    const ushort* HBb  = HB  + ((size_t)b << 11) * H + c8;   // E = 2048
    const int* agm = ag + (size_t)m * NB;
    const int* bgm = bg + (size_t)m * NB;

    int2 ia0 = *(const int2*)(agm + 0), ib0 = *(const int2*)(bgm + 0);
    int2 ia1 = *(const int2*)(agm + 2), ib1 = *(const int2*)(bgm + 2);
    int2 ia2 = *(const int2*)(agm + 4), ib2 = *(const int2*)(bgm + 4);
    int2 ia3 = *(const int2*)(agm + 6), ib3 = *(const int2*)(bgm + 6);
    int2 ia4 = *(const int2*)(agm + 8), ib4 = *(const int2*)(bgm + 8);

    float sacc[8], facc[8];
    #pragma unroll
    for (int i = 0; i < 8; ++i) { sacc[i] = 0.f; facc[i] = 0.f; }

    #define GL_STEP(nb, ia, ib)                                          \
    {                                                                    \
        const float w = ((nb) < nnb) ? 1.f : 0.f;                        \
        s16x8 av = *(const s16x8*)(AFb  + (size_t)(ia) * H);             \
        s16x8 tv = *(const s16x8*)(ATWb + (size_t)(ia) * H);             \
        s16x8 hv = *(const s16x8*)(HBb  + (size_t)(ib) * H);             \
        _Pragma("unroll")                                                \
        for (int i = 0; i < 8; ++i) {                                    \
            sacc[i] += w * b2f((ushort)av[i]);                           \
            facc[i] += (w * b2f((ushort)tv[i])) * b2f((ushort)hv[i]);    \
        }                                                                \
    }
    GL_STEP(0, ia0.x, ib0.x) GL_STEP(1, ia0.y, ib0.y)
    GL_STEP(2, ia1.x, ib1.x) GL_STEP(3, ia1.y, ib1.y)
    GL_STEP(4, ia2.x, ib2.x) GL_STEP(5, ia2.y, ib2.y)
    GL_STEP(6, ia3.x, ib3.x) GL_STEP(7, ia3.y, ib3.y)
    GL_STEP(8, ia4.x, ib4.x) GL_STEP(9, ia4.y, ib4.y)
    #undef GL_STEP

    s16x8 so, fo;
    #pragma unroll
    for (int i = 0; i < 8; ++i) { so[i] = (short)f2b(sacc[i]); fo[i] = (short)f2b(facc[i]); }
    *(s16x8*)(SATOM + (size_t)m * H + c8) = so;
    *(s16x8*)(FNEIb + (size_t)m * H + c8) = fo;
}

// ---------------------------------------------------------------------------
// HB[b][e][:] = bond[b,e,:] @ W_nei_bond  (bf16)  — loop-invariant precompute
// ---------------------------------------------------------------------------
__global__ __launch_bounds__(256) void prep_hb(
    const float* __restrict__ bond, const float* __restrict__ Wnb,
    ushort* __restrict__ HB)
{
    const int t = blockIdx.x * 256 + threadIdx.x;    // B*E*16 threads
    const int r = t >> 4, c8 = (t & 15) * 8;
    const float* fb = bond + (size_t)r * 6;
    const float2 f01 = *(const float2*)fb;
    const float2 f23 = *(const float2*)(fb + 2);
    const float2 f45 = *(const float2*)(fb + 4);
    s16x8 o;
    #pragma unroll
    for (int i = 0; i < 8; ++i) {
        const int c = c8 + i;
        const float v = f01.x * Wnb[0 * H + c] + f01.y * Wnb[1 * H + c]
                      + f23.x * Wnb[2 * H + c] + f23.y * Wnb[3 * H + c]
                      + f45.x * Wnb[4 * H + c] + f45.y * Wnb[5 * H + c];
        o[i] = (short)f2b(v);
    }
    *(s16x8*)(HB + (size_t)r * H + c8) = o;
}

// FBS8[m][8] = bf16[ sum_nb bond[bg[m,nb]][0..5], num_nbs, 0 ]
__global__ __launch_bounds__(256) void prep_fbs(
    const float* __restrict__ bond, const int* __restrict__ bg,
    const int* __restrict__ nn, ushort* __restrict__ FBSb)
{
    const int m = blockIdx.x * 256 + threadIdx.x;
    const int b = m >> 10;
    const int nnb = nn[m];
    float s[6] = {0,0,0,0,0,0};
    for (int nb = 0; nb < nnb; ++nb) {
        const int ib = bg[m * NB + nb];
        const float* fb = bond + ((size_t)(b << 11) + (size_t)ib) * 6;
        #pragma unroll
        for (int j = 0; j < 6; ++j) s[j] += fb[j];
    }
    s16x8 o;
    #pragma unroll
    for (int j = 0; j < 6; ++j) o[j] = (short)f2b(s[j]);
    o[6] = (short)f2b((float)nnb);
    o[7] = 0;
    *(s16x8*)(FBSb + (size_t)m * 8) = o;
}

// input_atom [M][82] f32 -> [M][96] bf16 (zero-padded)
__global__ __launch_bounds__(256) void cvt_atom(
    const float* __restrict__ ia, ushort* __restrict__ out)
{
    const int tid = blockIdx.x * 256 + threadIdx.x;   // M*12
    const int m = tid / 12, c = (tid % 12) * 8;
    s16x8 v;
    #pragma unroll
    for (int i = 0; i < 8; ++i) {
        const int k = c + i;
        v[i] = (short)(k < 82 ? f2b(ia[(size_t)m * 82 + k]) : 0);
    }
    *(s16x8*)(out + (size_t)m * 96 + c) = v;
}

// Transposed bf16 weights:
// WTa[128][96] | WTna[128][128] | WTslf[128][128] | WTu2a[128][128]
// | WTu1s[128][256] | WT2p[128][32]   (total 98304 elems)
__global__ __launch_bounds__(256) void prep_w(
    const float* __restrict__ Wa, const float* __restrict__ Wna,
    const float* __restrict__ Ws, const float* __restrict__ Wu2,
    const float* __restrict__ bu2, const float* __restrict__ Wu1,
    ushort* __restrict__ out)
{
    int t = blockIdx.x * 256 + threadIdx.x;
    const int tid = t;
    if (t < 128 * 96) { int n = t / 96, k = t % 96;
        out[tid] = (k < 82) ? f2b(Wa[k * H + n]) : 0; return; }
    t -= 128 * 96;
    if (t < 128 * 128) { int n = t / 128, k = t % 128;
        out[tid] = f2b(Wna[k * H + n]); return; }
    t -= 128 * 128;
    if (t < 128 * 128) { int n = t / 128, k = t % 128;
        out[tid] = f2b(Ws[k * H + n]); return; }
    t -= 128 * 128;
    if (t < 128 * 128) { int n = t / 128, k = t % 128;
        out[tid] = f2b(Wu2[k * H + n]); return; }
    t -= 128 * 128;
    if (t < 128 * 256) { int n = t / 256, k = t % 256;
        out[tid] = f2b(Wu1[k * H + n]); return; }
    t -= 128 * 256;
    if (t < 128 * 32) { int n = t / 32, j = t % 32;
        ushort v = 0;
        if (j < 6) v = f2b(Wu2[(128 + j) * H + n]);
        else if (j == 6) v = f2b(bu2[n]);
        out[tid] = v; return; }
}

// ---------------------------------------------------------------------------
extern "C" void kernel_launch(void* const* d_in, const int* in_sizes, int n_in,
                              void* d_out, int out_size, void* d_ws, size_t ws_size,
                              hipStream_t stream)
{
    (void)in_sizes; (void)n_in; (void)out_size; (void)ws_size;

    const float* input_atom = (const float*)d_in[0];
    const float* input_bond = (const float*)d_in[1];
    const int*   atom_graph = (const int*)d_in[2];
    const int*   bond_graph = (const int*)d_in[3];
    const int*   num_nbs    = (const int*)d_in[4];
    const float* node_mask  = (const float*)d_in[5];
    const float* W_atom     = (const float*)d_in[6];
    const float* W_nei_atom = (const float*)d_in[7];
    const float* W_nei_bond = (const float*)d_in[8];
    const float* W_self     = (const float*)d_in[9];
    const float* W_U2       = (const float*)d_in[10];
    const float* b_U2       = (const float*)d_in[11];
    const float* W_U1       = (const float*)d_in[12];
    const float* b_U1       = (const float*)d_in[13];

    char* ws = (char*)d_ws;
    ushort* AF0   = (ushort*)(ws);               // 16 MB
    ushort* AF1   = (ushort*)(ws + SL * 2);      // 16 MB
    ushort* NLBL  = (ushort*)(ws + SL * 4);      // 16 MB
    ushort* ATW   = (ushort*)(ws + SL * 6);      // 16 MB (last depth)
    ushort* AFin  = (ushort*)(ws + SL * 6);      // 12 MB (dead after FA gemm)
    ushort* HB    = (ushort*)(ws + SL * 2);      // 32 MB over AF1+NLBL (last depth;
                                                 //  AF1 dead, NLBL rewritten after)
    ushort* FBSb  = (ushort*)(ws + SL * 8);      // 1 MB
    ushort* WTs_  = (ushort*)(ws + SL * 8 + (size_t)M * 8 * 2);

    ushort* WTa   = WTs_;                        // [128][96]
    ushort* WTna  = WTa   + 128 * 96;            // [128][128]
    ushort* WTslf = WTna  + 128 * 128;
    ushort* WTu2a = WTslf + 128 * 128;
    ushort* WTu1s = WTu2a + 128 * 128;           // [128][256]
    ushort* WT2p  = WTu1s + 128 * 256;           // [128][32]

    float*  out0  = (float*)d_out;               // kernel [M][128] f32
    float*  out1  = out0 + SL;                   // atom_features [M][128] f32
    ushort* SATOM = (ushort*)out0;               // scratch bf16 (pre-KOUT)
    ushort* FNEIb = (ushort*)out1;               // scratch bf16 (pre-final-U1)

    prep_w<<<384, 256, 0, stream>>>(W_atom, W_nei_atom, W_self, W_U2, b_U2, W_U1, WTs_);
    cvt_atom<<<3072, 256, 0, stream>>>(input_atom, AFin);
    prep_fbs<<<256, 256, 0, stream>>>(input_bond, bond_graph, num_nbs, FBSb);

    // AF0 = input_atom @ W_atom   (K=96 padded)
    gemm_mf<3, 0><<<1024, 256, 0, stream>>>(AFin, WTa, nullptr, nullptr,
                                            nullptr, nullptr, nullptr, AF0);

    ushort* AF  = AF0;
    ushort* AFn = AF1;
    for (int d = 0; d < 2; ++d) {
        gather_satom<<<4096, 256, 0, stream>>>(AF, atom_graph, num_nbs, SATOM);
        gemm_mf<4, 1><<<1024, 256, 0, stream>>>(SATOM, WTu2a, FBSb, WT2p,
                                                nullptr, nullptr, nullptr, NLBL);
        k2_u1<false><<<2048, 256, 0, stream>>>(AF, NLBL, WTu1s, b_U1, nullptr, AFn);
        ushort* t = AF; AF = AFn; AFn = t;
    }
    // after 2 swaps: AF = AF0, AF1 dead -> HB may use AF1+NLBL region

    // ---- last depth ----
    gemm_mf<4, 0><<<1024, 256, 0, stream>>>(AF, WTna, nullptr, nullptr,
                                            nullptr, nullptr, nullptr, ATW);
    prep_hb<<<8192, 256, 0, stream>>>(input_bond, W_nei_bond, HB);
    gather_last<<<4096, 256, 0, stream>>>(AF, ATW, HB, atom_graph, bond_graph,
                                          num_nbs, SATOM, FNEIb);
    gemm_mf<4, 1><<<1024, 256, 0, stream>>>(SATOM, WTu2a, FBSb, WT2p,
                                            nullptr, nullptr, nullptr, NLBL);
    // kernel = (AF @ W_self) * FNEI * node_mask -> out0 (reads FNEIb=out1 low half)
    gemm_mf<4, 8 | 16><<<1024, 256, 0, stream>>>(AF, WTslf, nullptr, nullptr,
                                                 FNEIb, node_mask, out0, nullptr);
    // atom_features = [AF|NLBL] @ W_U1 + b_U1 -> out1 (clobbers FNEIb, now dead)
    k2_u1<true><<<2048, 256, 0, stream>>>(AF, NLBL, WTu1s, b_U1, out1, nullptr);
}

// Round 5
// 216.945 us; speedup vs baseline: 1.6481x; 1.5835x over previous
//
#include <hip/hip_runtime.h>

constexpr int NB = 10, H = 128;
constexpr int M = 64 * 1024;             // B*A rows
constexpr long SL = (long)M * H;         // elems per [M,H] matrix

typedef __attribute__((ext_vector_type(8))) short s16x8;
typedef __attribute__((ext_vector_type(4))) float f32x4;

__device__ __forceinline__ ushort f2b(float f) {
    union { float f; uint u; } v; v.f = f;
    uint u = v.u;
    uint r = u + 0x7fffu + ((u >> 16) & 1u);
    return (ushort)(r >> 16);
}
__device__ __forceinline__ float b2f(ushort u) {
    union { uint u; float f; } v; v.u = ((uint)u) << 16; return v.f;
}

// XCD-chunked bijective swizzle (grid % 8 == 0)
__device__ __forceinline__ int swz(int bid, int cpx) {
    return (bid & 7) * cpx + (bid >> 3);
}

// ---------------------------------------------------------------------------
// Grid-stride MFMA GEMM: C[M][128] = A[M][K=NC*32] @ W  (WT=[128][K] bf16).
// 1024 blocks x 4 waves; wave owns 32 cols (2 coltiles), weights resident in
// VGPRs, loops 4 row-tiles with A-prefetch.  FLAGS: 8=KOUT, 16=OF32.
// ---------------------------------------------------------------------------
template<int NC, int FLAGS>
__global__ __launch_bounds__(256, 4) void gemm_af(
    const ushort* __restrict__ Abf, const ushort* __restrict__ WT,
    const ushort* __restrict__ FNb, const float* __restrict__ nmask,
    float* __restrict__ Cf, ushort* __restrict__ Cb)
{
    constexpr bool KOUT = FLAGS & 8, OF32 = FLAGS & 16;
    constexpr int K = NC * 32;
    const int lane = threadIdx.x & 63, wid = threadIdx.x >> 6;
    const int l15 = lane & 15, g = lane >> 4;
    const int t0 = swz(blockIdx.x, 128) * 4;

    s16x8 w[2][NC];
    #pragma unroll
    for (int ct = 0; ct < 2; ++ct)
        #pragma unroll
        for (int kc = 0; kc < NC; ++kc)
            w[ct][kc] = *(const s16x8*)(WT + (size_t)((2 * wid + ct) * 16 + l15) * K + kc * 32 + g * 8);

    s16x8 ac[NC], an[NC];
    #pragma unroll
    for (int kc = 0; kc < NC; ++kc)
        ac[kc] = *(const s16x8*)(Abf + (size_t)(t0 * 16 + l15) * K + kc * 32 + g * 8);

    #pragma unroll
    for (int i = 0; i < 4; ++i) {
        const int m0 = (t0 + i) * 16;
        if (i < 3) {
            #pragma unroll
            for (int kc = 0; kc < NC; ++kc)
                an[kc] = *(const s16x8*)(Abf + (size_t)(m0 + 16 + l15) * K + kc * 32 + g * 8);
        }
        f32x4 acc[2];
        #pragma unroll
        for (int ct = 0; ct < 2; ++ct) acc[ct] = (f32x4){0.f, 0.f, 0.f, 0.f};
        #pragma unroll
        for (int kc = 0; kc < NC; ++kc)
            #pragma unroll
            for (int ct = 0; ct < 2; ++ct)
                acc[ct] = __builtin_amdgcn_mfma_f32_16x16x32_bf16(ac[kc], w[ct][kc], acc[ct], 0, 0, 0);

        #pragma unroll
        for (int ct = 0; ct < 2; ++ct) {
            const int col = (2 * wid + ct) * 16 + l15;
            #pragma unroll
            for (int r = 0; r < 4; ++r) {
                const int m = m0 + 4 * g + r;
                const size_t o = (size_t)m * H + col;
                float v = acc[ct][r];
                if constexpr (KOUT) v = v * b2f(FNb[o]) * nmask[m];
                if constexpr (OF32) Cf[o] = v; else Cb[o] = f2b(v);
            }
        }
        #pragma unroll
        for (int kc = 0; kc < NC; ++kc) ac[kc] = an[kc];
    }
}

// ---------------------------------------------------------------------------
// Fused composed-U1:  out = AF@Wu1a + SATOM@Wc + FBS8@W2c
// (Wc = Wu2a@Wu1b; W2c rows: Wu2[128+j]@Wu1b, b_U2@Wu1b, b_U1; FBS8[7]=1)
// K = 288 = 4(AF) + 4(SATOM) + 1(FBS) chunks.  WT layout [128 cols][288].
// ---------------------------------------------------------------------------
template<bool OF32>
__global__ __launch_bounds__(256, 2) void u1f(
    const ushort* __restrict__ AF, const ushort* __restrict__ SATOM,
    const ushort* __restrict__ FBSb, const ushort* __restrict__ WT,
    float* __restrict__ Cf, ushort* __restrict__ Cb)
{
    const int lane = threadIdx.x & 63, wid = threadIdx.x >> 6;
    const int l15 = lane & 15, g = lane >> 4;
    const int t0 = swz(blockIdx.x, 128) * 4;

    s16x8 w[2][9];
    #pragma unroll
    for (int ct = 0; ct < 2; ++ct)
        #pragma unroll
        for (int kc = 0; kc < 9; ++kc)
            w[ct][kc] = *(const s16x8*)(WT + (size_t)((2 * wid + ct) * 16 + l15) * 288 + kc * 32 + g * 8);

    s16x8 ac[9], an[9];
    {
        const size_t rb = (size_t)(t0 * 16 + l15) * H + g * 8;
        #pragma unroll
        for (int kc = 0; kc < 4; ++kc) {
            ac[kc]     = *(const s16x8*)(AF    + rb + kc * 32);
            ac[kc + 4] = *(const s16x8*)(SATOM + rb + kc * 32);
        }
        ac[8] = (s16x8){0,0,0,0,0,0,0,0};
        if (g == 0) ac[8] = *(const s16x8*)(FBSb + (size_t)(t0 * 16 + l15) * 8);
    }

    #pragma unroll
    for (int i = 0; i < 4; ++i) {
        const int m0 = (t0 + i) * 16;
        if (i < 3) {
            const size_t rb = (size_t)(m0 + 16 + l15) * H + g * 8;
            #pragma unroll
            for (int kc = 0; kc < 4; ++kc) {
                an[kc]     = *(const s16x8*)(AF    + rb + kc * 32);
                an[kc + 4] = *(const s16x8*)(SATOM + rb + kc * 32);
            }
            an[8] = (s16x8){0,0,0,0,0,0,0,0};
            if (g == 0) an[8] = *(const s16x8*)(FBSb + (size_t)(m0 + 16 + l15) * 8);
        }
        f32x4 acc[2];
        #pragma unroll
        for (int ct = 0; ct < 2; ++ct) acc[ct] = (f32x4){0.f, 0.f, 0.f, 0.f};
        #pragma unroll
        for (int kc = 0; kc < 9; ++kc)
            #pragma unroll
            for (int ct = 0; ct < 2; ++ct)
                acc[ct] = __builtin_amdgcn_mfma_f32_16x16x32_bf16(ac[kc], w[ct][kc], acc[ct], 0, 0, 0);

        #pragma unroll
        for (int ct = 0; ct < 2; ++ct) {
            const int col = (2 * wid + ct) * 16 + l15;
            #pragma unroll
            for (int r = 0; r < 4; ++r) {
                const size_t o = (size_t)(m0 + 4 * g + r) * H + col;
                if constexpr (OF32) Cf[o] = acc[ct][r]; else Cb[o] = f2b(acc[ct][r]);
            }
        }
        #pragma unroll
        for (int kc = 0; kc < 9; ++kc) ac[kc] = an[kc];
    }
}

// ---------------------------------------------------------------------------
// SATOM gather: SATOM[m][:] = sum_{nb<nnb} AF[b, ag[m,nb]][:]  (bf16)
// ---------------------------------------------------------------------------
__global__ __launch_bounds__(256, 6) void gather_satom(
    const ushort* __restrict__ AF, const int* __restrict__ ag,
    const int* __restrict__ nn, ushort* __restrict__ SATOM)
{
    const int bid = swz(blockIdx.x, 512);
    const int m  = bid * 16 + (threadIdx.x >> 4);
    const int c8 = (threadIdx.x & 15) * 8;
    const int b  = m >> 10;
    const int nnb = nn[m];
    const ushort* AFb = AF + ((size_t)b << 10) * H + c8;
    const int* agm = ag + (size_t)m * NB;

    int2 iv0 = *(const int2*)(agm + 0);
    int2 iv1 = *(const int2*)(agm + 2);
    int2 iv2 = *(const int2*)(agm + 4);
    int2 iv3 = *(const int2*)(agm + 6);
    int2 iv4 = *(const int2*)(agm + 8);

    float sacc[8];
    #pragma unroll
    for (int i = 0; i < 8; ++i) sacc[i] = 0.f;

    #define GS_STEP(nb, ia)                                              \
    {                                                                    \
        const float w = ((nb) < nnb) ? 1.f : 0.f;                        \
        s16x8 av = *(const s16x8*)(AFb + (size_t)(ia) * H);              \
        _Pragma("unroll")                                                \
        for (int i = 0; i < 8; ++i) sacc[i] += w * b2f((ushort)av[i]);   \
    }
    GS_STEP(0, iv0.x) GS_STEP(1, iv0.y)
    GS_STEP(2, iv1.x) GS_STEP(3, iv1.y)
    GS_STEP(4, iv2.x) GS_STEP(5, iv2.y)
    GS_STEP(6, iv3.x) GS_STEP(7, iv3.y)
    GS_STEP(8, iv4.x) GS_STEP(9, iv4.y)
    #undef GS_STEP

    s16x8 so;
    #pragma unroll
    for (int i = 0; i < 8; ++i) so[i] = (short)f2b(sacc[i]);
    *(s16x8*)(SATOM + (size_t)m * H + c8) = so;
}

// ---------------------------------------------------------------------------
// Last-depth gather: SATOM and FNEI = sum_nb ATW[ag]*HB[bg]  (both bf16 out)
// ---------------------------------------------------------------------------
__global__ __launch_bounds__(256, 4) void gather_last(
    const ushort* __restrict__ AF, const ushort* __restrict__ ATW,
    const ushort* __restrict__ HB, const int* __restrict__ ag,
    const int* __restrict__ bg, const int* __restrict__ nn,
    ushort* __restrict__ SATOM, ushort* __restrict__ FNEIb)
{
    const int bid = swz(blockIdx.x, 512);
    const int m  = bid * 16 + (threadIdx.x >> 4);
    const int c8 = (threadIdx.x & 15) * 8;
    const int b  = m >> 10;
    const int nnb = nn[m];
    const ushort* AFb  = AF  + ((size_t)b << 10) * H + c8;
    const ushort* ATWb = ATW + ((size_t)b << 10) * H + c8;
    const ushort* HBb  = HB  + ((size_t)b << 11) * H + c8;   // E = 2048
    const int* agm = ag + (size_t)m * NB;
    const int* bgm = bg + (size_t)m * NB;

    int2 ia0 = *(const int2*)(agm + 0), ib0 = *(const int2*)(bgm + 0);
    int2 ia1 = *(const int2*)(agm + 2), ib1 = *(const int2*)(bgm + 2);
    int2 ia2 = *(const int2*)(agm + 4), ib2 = *(const int2*)(bgm + 4);
    int2 ia3 = *(const int2*)(agm + 6), ib3 = *(const int2*)(bgm + 6);
    int2 ia4 = *(const int2*)(agm + 8), ib4 = *(const int2*)(bgm + 8);

    float sacc[8], facc[8];
    #pragma unroll
    for (int i = 0; i < 8; ++i) { sacc[i] = 0.f; facc[i] = 0.f; }

    #define GL_STEP(nb, ia, ib)                                          \
    {                                                                    \
        const float w = ((nb) < nnb) ? 1.f : 0.f;                        \
        s16x8 av = *(const s16x8*)(AFb  + (size_t)(ia) * H);             \
        s16x8 tv = *(const s16x8*)(ATWb + (size_t)(ia) * H);             \
        s16x8 hv = *(const s16x8*)(HBb  + (size_t)(ib) * H);             \
        _Pragma("unroll")                                                \
        for (int i = 0; i < 8; ++i) {                                    \
            sacc[i] += w * b2f((ushort)av[i]);                           \
            facc[i] += (w * b2f((ushort)tv[i])) * b2f((ushort)hv[i]);    \
        }                                                                \
    }
    GL_STEP(0, ia0.x, ib0.x) GL_STEP(1, ia0.y, ib0.y)
    GL_STEP(2, ia1.x, ib1.x) GL_STEP(3, ia1.y, ib1.y)
    GL_STEP(4, ia2.x, ib2.x) GL_STEP(5, ia2.y, ib2.y)
    GL_STEP(6, ia3.x, ib3.x) GL_STEP(7, ia3.y, ib3.y)
    GL_STEP(8, ia4.x, ib4.x) GL_STEP(9, ia4.y, ib4.y)
    #undef GL_STEP

    s16x8 so, fo;
    #pragma unroll
    for (int i = 0; i < 8; ++i) { so[i] = (short)f2b(sacc[i]); fo[i] = (short)f2b(facc[i]); }
    *(s16x8*)(SATOM + (size_t)m * H + c8) = so;
    *(s16x8*)(FNEIb + (size_t)m * H + c8) = fo;
}

// ---------------------------------------------------------------------------
// HB[b][e][:] = bond[b,e,:] @ W_nei_bond  (bf16)
// ---------------------------------------------------------------------------
__global__ __launch_bounds__(256) void prep_hb(
    const float* __restrict__ bond, const float* __restrict__ Wnb,
    ushort* __restrict__ HB)
{
    const int t = blockIdx.x * 256 + threadIdx.x;    // B*E*16 threads
    const int r = t >> 4, c8 = (t & 15) * 8;
    const float* fb = bond + (size_t)r * 6;
    const float2 f01 = *(const float2*)fb;
    const float2 f23 = *(const float2*)(fb + 2);
    const float2 f45 = *(const float2*)(fb + 4);
    s16x8 o;
    #pragma unroll
    for (int i = 0; i < 8; ++i) {
        const int c = c8 + i;
        const float v = f01.x * Wnb[0 * H + c] + f01.y * Wnb[1 * H + c]
                      + f23.x * Wnb[2 * H + c] + f23.y * Wnb[3 * H + c]
                      + f45.x * Wnb[4 * H + c] + f45.y * Wnb[5 * H + c];
        o[i] = (short)f2b(v);
    }
    *(s16x8*)(HB + (size_t)r * H + c8) = o;
}

// FBS8[m][8] = bf16[ sum_nb bond[bg[m,nb]][0..5], num_nbs, 1 ]
__global__ __launch_bounds__(256) void prep_fbs(
    const float* __restrict__ bond, const int* __restrict__ bg,
    const int* __restrict__ nn, ushort* __restrict__ FBSb)
{
    const int m = blockIdx.x * 256 + threadIdx.x;
    const int b = m >> 10;
    const int nnb = nn[m];
    float s[6] = {0,0,0,0,0,0};
    for (int nb = 0; nb < nnb; ++nb) {
        const int ib = bg[m * NB + nb];
        const float* fb = bond + ((size_t)(b << 11) + (size_t)ib) * 6;
        #pragma unroll
        for (int j = 0; j < 6; ++j) s[j] += fb[j];
    }
    s16x8 o;
    #pragma unroll
    for (int j = 0; j < 6; ++j) o[j] = (short)f2b(s[j]);
    o[6] = (short)f2b((float)nnb);
    o[7] = (short)f2b(1.0f);
    *(s16x8*)(FBSb + (size_t)m * 8) = o;
}

// input_atom [M][82] f32 -> [M][96] bf16 (zero-padded)
__global__ __launch_bounds__(256) void cvt_atom(
    const float* __restrict__ ia, ushort* __restrict__ out)
{
    const int tid = blockIdx.x * 256 + threadIdx.x;   // M*12
    const int m = tid / 12, c = (tid % 12) * 8;
    s16x8 v;
    #pragma unroll
    for (int i = 0; i < 8; ++i) {
        const int k = c + i;
        v[i] = (short)(k < 82 ? f2b(ia[(size_t)m * 82 + k]) : 0);
    }
    *(s16x8*)(out + (size_t)m * 96 + c) = v;
}

// Transposed bf16 weights + composed U1 weights:
// WTa[128][96] | WTna[128][128] | WTslf[128][128] | WTu1f[128][288]
//   WTu1f col n: k<128: Wu1a[k][n]; k<256: Wc[k-128][n]=(Wu2a@Wu1b)[.][n];
//   k=256+j: j<6: (Wu2[128+j]@Wu1b)[n]; j=6: (b_U2@Wu1b)[n]; j=7: b_U1[n]; else 0
__global__ __launch_bounds__(256) void prep_w(
    const float* __restrict__ Wa, const float* __restrict__ Wna,
    const float* __restrict__ Ws, const float* __restrict__ Wu2,
    const float* __restrict__ bu2, const float* __restrict__ Wu1,
    const float* __restrict__ bu1, ushort* __restrict__ out)
{
    int t = blockIdx.x * 256 + threadIdx.x;
    const int tid = t;
    if (t < 128 * 96) { int n = t / 96, k = t % 96;
        out[tid] = (k < 82) ? f2b(Wa[k * H + n]) : 0; return; }
    t -= 128 * 96;
    if (t < 128 * 128) { int n = t / 128, k = t % 128;
        out[tid] = f2b(Wna[k * H + n]); return; }
    t -= 128 * 128;
    if (t < 128 * 128) { int n = t / 128, k = t % 128;
        out[tid] = f2b(Ws[k * H + n]); return; }
    t -= 128 * 128;
    if (t < 128 * 288) {
        const int n = t / 288, k = t % 288;
        float v = 0.f;
        if (k < 128) {
            v = Wu1[k * H + n];
        } else if (k < 256) {
            const int kk = k - 128;
            float s = 0.f;
            for (int j = 0; j < 128; ++j) s += Wu2[kk * H + j] * Wu1[(128 + j) * H + n];
            v = s;
        } else {
            const int j = k - 256;
            if (j < 6) {
                float s = 0.f;
                for (int q = 0; q < 128; ++q) s += Wu2[(128 + j) * H + q] * Wu1[(128 + q) * H + n];
                v = s;
            } else if (j == 6) {
                float s = 0.f;
                for (int q = 0; q < 128; ++q) s += bu2[q] * Wu1[(128 + q) * H + n];
                v = s;
            } else if (j == 7) {
                v = bu1[n];
            }
        }
        out[tid] = f2b(v);
        return;
    }
}

// ---------------------------------------------------------------------------
extern "C" void kernel_launch(void* const* d_in, const int* in_sizes, int n_in,
                              void* d_out, int out_size, void* d_ws, size_t ws_size,
                              hipStream_t stream)
{
    (void)in_sizes; (void)n_in; (void)out_size; (void)ws_size;

    const float* input_atom = (const float*)d_in[0];
    const float* input_bond = (const float*)d_in[1];
    const int*   atom_graph = (const int*)d_in[2];
    const int*   bond_graph = (const int*)d_in[3];
    const int*   num_nbs    = (const int*)d_in[4];
    const float* node_mask  = (const float*)d_in[5];
    const float* W_atom     = (const float*)d_in[6];
    const float* W_nei_atom = (const float*)d_in[7];
    const float* W_nei_bond = (const float*)d_in[8];
    const float* W_self     = (const float*)d_in[9];
    const float* W_U2       = (const float*)d_in[10];
    const float* b_U2       = (const float*)d_in[11];
    const float* W_U1       = (const float*)d_in[12];
    const float* b_U1       = (const float*)d_in[13];

    char* ws = (char*)d_ws;
    ushort* AF0   = (ushort*)(ws);               // 16 MB
    ushort* AF1   = (ushort*)(ws + SL * 2);      // 16 MB (FNEI scratch at last depth)
    ushort* SATw  = (ushort*)(ws + SL * 4);      // 16 MB (SATOM d0/d1; ATW at last)
    ushort* ATW   = SATw;
    ushort* HB    = (ushort*)(ws + SL * 6);      // 32 MB  (AFin overlaps: dead first)
    ushort* AFin  = (ushort*)(ws + SL * 6);      // 12 MB
    ushort* FBSb  = (ushort*)(ws + SL * 10);     // 1 MB
    ushort* WTs_  = (ushort*)(ws + SL * 10 + (size_t)M * 8 * 2);

    ushort* WTa   = WTs_;                        // [128][96]
    ushort* WTna  = WTa   + 128 * 96;            // [128][128]
    ushort* WTslf = WTna  + 128 * 128;           // [128][128]
    ushort* WTu1f = WTslf + 128 * 128;           // [128][288]

    float*  out0  = (float*)d_out;               // kernel [M][128] f32
    float*  out1  = out0 + SL;                   // atom_features [M][128] f32
    ushort* SATl  = (ushort*)out0;               // last-depth SATOM scratch (bf16)
    ushort* FNEIb = AF1;                         // last-depth FNEI scratch (bf16)

    prep_w<<<320, 256, 0, stream>>>(W_atom, W_nei_atom, W_self, W_U2, b_U2,
                                    W_U1, b_U1, WTs_);
    cvt_atom<<<3072, 256, 0, stream>>>(input_atom, AFin);
    prep_fbs<<<256, 256, 0, stream>>>(input_bond, bond_graph, num_nbs, FBSb);

    // AF0 = input_atom @ W_atom   (K=96 padded)
    gemm_af<3, 0><<<1024, 256, 0, stream>>>(AFin, WTa, nullptr, nullptr,
                                            nullptr, AF0);

    // depth 0
    gather_satom<<<4096, 256, 0, stream>>>(AF0, atom_graph, num_nbs, SATw);
    u1f<false><<<1024, 256, 0, stream>>>(AF0, SATw, FBSb, WTu1f, nullptr, AF1);
    // depth 1
    gather_satom<<<4096, 256, 0, stream>>>(AF1, atom_graph, num_nbs, SATw);
    u1f<false><<<1024, 256, 0, stream>>>(AF1, SATw, FBSb, WTu1f, nullptr, AF0);

    // ---- last depth (AF = AF0; AF1 dead -> FNEI scratch) ----
    gemm_af<4, 0><<<1024, 256, 0, stream>>>(AF0, WTna, nullptr, nullptr,
                                            nullptr, ATW);
    prep_hb<<<8192, 256, 0, stream>>>(input_bond, W_nei_bond, HB);
    gather_last<<<4096, 256, 0, stream>>>(AF0, ATW, HB, atom_graph, bond_graph,
                                          num_nbs, SATl, FNEIb);
    // atom_features -> out1 (f32); reads SATl(out0) BEFORE out0 is overwritten
    u1f<true><<<1024, 256, 0, stream>>>(AF0, SATl, FBSb, WTu1f, out1, nullptr);
    // kernel = (AF @ W_self) * FNEI * node_mask -> out0 (f32)
    gemm_af<4, 8 | 16><<<1024, 256, 0, stream>>>(AF0, WTslf, FNEIb, node_mask,
                                                 out0, nullptr);
}

// Round 6
// 193.305 us; speedup vs baseline: 1.8497x; 1.1223x over previous
//
#include <hip/hip_runtime.h>

constexpr int NB = 10, H = 128;
constexpr int M = 64 * 1024;             // B*A rows
constexpr long SL = (long)M * H;         // elems per [M,H] matrix

typedef __attribute__((ext_vector_type(8))) short s16x8;
typedef __attribute__((ext_vector_type(4))) float f32x4;

__device__ __forceinline__ ushort f2b(float f) {
    union { float f; uint u; } v; v.f = f;
    uint u = v.u;
    uint r = u + 0x7fffu + ((u >> 16) & 1u);
    return (ushort)(r >> 16);
}
__device__ __forceinline__ float b2f(ushort u) {
    union { uint u; float f; } v; v.u = ((uint)u) << 16; return v.f;
}

// XCD-chunked bijective swizzle (sub-grid % 8 == 0, sub-grid base % 8 == 0)
__device__ __forceinline__ int swz(int bid, int cpx) {
    return (bid & 7) * cpx + (bid >> 3);
}

// ---------------------------------------------------------------------------
// GEMM body: C[128 cols] = A[M][K=NC*32] @ W (WT=[128][K] bf16).
// Wave owns 32 cols (weights resident), walks 4 row-tiles.
// FLAGS: 8=KOUT (v *= b2f(FN)*nmask), 16=OF32
// ---------------------------------------------------------------------------
template<int NC, int FLAGS>
__device__ __forceinline__ void gemm_body(
    int tg, const ushort* __restrict__ Abf, const ushort* __restrict__ WT,
    const ushort* __restrict__ FNb, const float* __restrict__ nmask,
    float* __restrict__ Cf, ushort* __restrict__ Cb)
{
    constexpr bool KOUT = FLAGS & 8, OF32 = FLAGS & 16;
    constexpr int K = NC * 32;
    const int lane = threadIdx.x & 63, wid = threadIdx.x >> 6;
    const int l15 = lane & 15, g = lane >> 4;

    s16x8 w[2][NC];
    #pragma unroll
    for (int ct = 0; ct < 2; ++ct)
        #pragma unroll
        for (int kc = 0; kc < NC; ++kc)
            w[ct][kc] = *(const s16x8*)(WT + (size_t)((2 * wid + ct) * 16 + l15) * K + kc * 32 + g * 8);

    #pragma unroll
    for (int i = 0; i < 4; ++i) {
        const int m0 = (tg * 4 + i) * 16;
        s16x8 ac[NC];
        #pragma unroll
        for (int kc = 0; kc < NC; ++kc)
            ac[kc] = *(const s16x8*)(Abf + (size_t)(m0 + l15) * K + kc * 32 + g * 8);

        f32x4 acc[2];
        #pragma unroll
        for (int ct = 0; ct < 2; ++ct) acc[ct] = (f32x4){0.f, 0.f, 0.f, 0.f};
        #pragma unroll
        for (int kc = 0; kc < NC; ++kc)
            #pragma unroll
            for (int ct = 0; ct < 2; ++ct)
                acc[ct] = __builtin_amdgcn_mfma_f32_16x16x32_bf16(ac[kc], w[ct][kc], acc[ct], 0, 0, 0);

        #pragma unroll
        for (int ct = 0; ct < 2; ++ct) {
            const int col = (2 * wid + ct) * 16 + l15;
            #pragma unroll
            for (int r = 0; r < 4; ++r) {
                const int m = m0 + 4 * g + r;
                const size_t o = (size_t)m * H + col;
                float v = acc[ct][r];
                if constexpr (KOUT) v = v * b2f(FNb[o]) * nmask[m];
                if constexpr (OF32) Cf[o] = v; else Cb[o] = f2b(v);
            }
        }
    }
}

// ---------------------------------------------------------------------------
// Composed-U1 body: out = AF@Wu1a + SATOM@Wc + FBS8@W2c   (K=288, 9 chunks)
// ---------------------------------------------------------------------------
template<bool OF32>
__device__ __forceinline__ void u1f_body(
    int tg, const ushort* __restrict__ AF, const ushort* __restrict__ SATOM,
    const ushort* __restrict__ FBSb, const ushort* __restrict__ WT,
    float* __restrict__ Cf, ushort* __restrict__ Cb)
{
    const int lane = threadIdx.x & 63, wid = threadIdx.x >> 6;
    const int l15 = lane & 15, g = lane >> 4;

    s16x8 w[2][9];
    #pragma unroll
    for (int ct = 0; ct < 2; ++ct)
        #pragma unroll
        for (int kc = 0; kc < 9; ++kc)
            w[ct][kc] = *(const s16x8*)(WT + (size_t)((2 * wid + ct) * 16 + l15) * 288 + kc * 32 + g * 8);

    #pragma unroll
    for (int i = 0; i < 4; ++i) {
        const int m0 = (tg * 4 + i) * 16;
        const size_t rb = (size_t)(m0 + l15) * H + g * 8;
        s16x8 ac[9];
        #pragma unroll
        for (int kc = 0; kc < 4; ++kc) {
            ac[kc]     = *(const s16x8*)(AF    + rb + kc * 32);
            ac[kc + 4] = *(const s16x8*)(SATOM + rb + kc * 32);
        }
        ac[8] = (s16x8){0,0,0,0,0,0,0,0};
        if (g == 0) ac[8] = *(const s16x8*)(FBSb + (size_t)(m0 + l15) * 8);

        f32x4 acc[2];
        #pragma unroll
        for (int ct = 0; ct < 2; ++ct) acc[ct] = (f32x4){0.f, 0.f, 0.f, 0.f};
        #pragma unroll
        for (int kc = 0; kc < 9; ++kc)
            #pragma unroll
            for (int ct = 0; ct < 2; ++ct)
                acc[ct] = __builtin_amdgcn_mfma_f32_16x16x32_bf16(ac[kc], w[ct][kc], acc[ct], 0, 0, 0);

        #pragma unroll
        for (int ct = 0; ct < 2; ++ct) {
            const int col = (2 * wid + ct) * 16 + l15;
            #pragma unroll
            for (int r = 0; r < 4; ++r) {
                const size_t o = (size_t)(m0 + 4 * g + r) * H + col;
                if constexpr (OF32) Cf[o] = acc[ct][r]; else Cb[o] = f2b(acc[ct][r]);
            }
        }
    }
}

template<int NC, int FLAGS>
__global__ __launch_bounds__(256, 4) void gemm_af(
    const ushort* __restrict__ Abf, const ushort* __restrict__ WT,
    const ushort* __restrict__ FNb, const float* __restrict__ nmask,
    float* __restrict__ Cf, ushort* __restrict__ Cb)
{
    gemm_body<NC, FLAGS>(swz(blockIdx.x, 128), Abf, WT, FNb, nmask, Cf, Cb);
}

template<bool OF32>
__global__ __launch_bounds__(256, 4) void u1f(
    const ushort* __restrict__ AF, const ushort* __restrict__ SATOM,
    const ushort* __restrict__ FBSb, const ushort* __restrict__ WT,
    float* __restrict__ Cf, ushort* __restrict__ Cb)
{
    u1f_body<OF32>(swz(blockIdx.x, 128), AF, SATOM, FBSb, WT, Cf, Cb);
}

// final2: blocks [0,1024): atom_features = [AF|SATl|FBS]@WTu1f -> out1 (f32)
//         blocks [1024,2048): kernel = (AF@Wslf)*FNEI*nmask   -> out0 (f32)
__global__ __launch_bounds__(256, 4) void final2(
    const ushort* __restrict__ AF, const ushort* __restrict__ SATl,
    const ushort* __restrict__ FBSb, const ushort* __restrict__ WTu1f,
    const ushort* __restrict__ WTslf, const ushort* __restrict__ FNEIb,
    const float* __restrict__ nmask, float* __restrict__ out1,
    float* __restrict__ out0)
{
    if (blockIdx.x < 1024)
        u1f_body<true>(swz(blockIdx.x, 128), AF, SATl, FBSb, WTu1f, out1, nullptr);
    else
        gemm_body<4, 8 | 16>(swz(blockIdx.x - 1024, 128), AF, WTslf, FNEIb,
                             nmask, out0, nullptr);
}

// ---------------------------------------------------------------------------
// SATOM gather: SATOM[m][:] = sum_{nb<nnb} AF[b, ag[m,nb]][:]  (bf16)
// 10 independent guarded blocks (exec-masked loads; no wasted traffic).
// ---------------------------------------------------------------------------
__global__ __launch_bounds__(256, 8) void gather_satom(
    const ushort* __restrict__ AF, const int* __restrict__ ag,
    const int* __restrict__ nn, ushort* __restrict__ SATOM)
{
    const int bid = swz(blockIdx.x, 512);
    const int m  = bid * 16 + (threadIdx.x >> 4);
    const int c8 = (threadIdx.x & 15) * 8;
    const int b  = m >> 10;
    const int nnb = nn[m];
    const ushort* AFb = AF + ((size_t)b << 10) * H + c8;
    const int* agm = ag + (size_t)m * NB;

    int2 iv0 = *(const int2*)(agm + 0);
    int2 iv1 = *(const int2*)(agm + 2);
    int2 iv2 = *(const int2*)(agm + 4);
    int2 iv3 = *(const int2*)(agm + 6);
    int2 iv4 = *(const int2*)(agm + 8);

    float sacc[8];
    #pragma unroll
    for (int i = 0; i < 8; ++i) sacc[i] = 0.f;

    #define GS_STEP(nb, ia)                                              \
    if ((nb) < nnb) {                                                    \
        s16x8 av = *(const s16x8*)(AFb + (size_t)(ia) * H);              \
        _Pragma("unroll")                                                \
        for (int i = 0; i < 8; ++i) sacc[i] += b2f((ushort)av[i]);       \
    }
    GS_STEP(0, iv0.x) GS_STEP(1, iv0.y)
    GS_STEP(2, iv1.x) GS_STEP(3, iv1.y)
    GS_STEP(4, iv2.x) GS_STEP(5, iv2.y)
    GS_STEP(6, iv3.x) GS_STEP(7, iv3.y)
    GS_STEP(8, iv4.x) GS_STEP(9, iv4.y)
    #undef GS_STEP

    s16x8 so;
    #pragma unroll
    for (int i = 0; i < 8; ++i) so[i] = (short)f2b(sacc[i]);
    *(s16x8*)(SATOM + (size_t)m * H + c8) = so;
}

// ---------------------------------------------------------------------------
// Last-depth gather: SATOM and FNEI = sum_nb ATW[ag]*HB[bg]  (both bf16 out)
// ---------------------------------------------------------------------------
__global__ __launch_bounds__(256, 4) void gather_last(
    const ushort* __restrict__ AF, const ushort* __restrict__ ATW,
    const ushort* __restrict__ HB, const int* __restrict__ ag,
    const int* __restrict__ bg, const int* __restrict__ nn,
    ushort* __restrict__ SATOM, ushort* __restrict__ FNEIb)
{
    const int bid = swz(blockIdx.x, 512);
    const int m  = bid * 16 + (threadIdx.x >> 4);
    const int c8 = (threadIdx.x & 15) * 8;
    const int b  = m >> 10;
    const int nnb = nn[m];
    const ushort* AFb  = AF  + ((size_t)b << 10) * H + c8;
    const ushort* ATWb = ATW + ((size_t)b << 10) * H + c8;
    const ushort* HBb  = HB  + ((size_t)b << 11) * H + c8;   // E = 2048
    const int* agm = ag + (size_t)m * NB;
    const int* bgm = bg + (size_t)m * NB;

    int2 ia0 = *(const int2*)(agm + 0), ib0 = *(const int2*)(bgm + 0);
    int2 ia1 = *(const int2*)(agm + 2), ib1 = *(const int2*)(bgm + 2);
    int2 ia2 = *(const int2*)(agm + 4), ib2 = *(const int2*)(bgm + 4);
    int2 ia3 = *(const int2*)(agm + 6), ib3 = *(const int2*)(bgm + 6);
    int2 ia4 = *(const int2*)(agm + 8), ib4 = *(const int2*)(bgm + 8);

    float sacc[8], facc[8];
    #pragma unroll
    for (int i = 0; i < 8; ++i) { sacc[i] = 0.f; facc[i] = 0.f; }

    #define GL_STEP(nb, ia, ib)                                          \
    if ((nb) < nnb) {                                                    \
        s16x8 av = *(const s16x8*)(AFb  + (size_t)(ia) * H);             \
        s16x8 tv = *(const s16x8*)(ATWb + (size_t)(ia) * H);             \
        s16x8 hv = *(const s16x8*)(HBb  + (size_t)(ib) * H);             \
        _Pragma("unroll")                                                \
        for (int i = 0; i < 8; ++i) {                                    \
            sacc[i] += b2f((ushort)av[i]);                               \
            facc[i] += b2f((ushort)tv[i]) * b2f((ushort)hv[i]);          \
        }                                                                \
    }
    GL_STEP(0, ia0.x, ib0.x) GL_STEP(1, ia0.y, ib0.y)
    GL_STEP(2, ia1.x, ib1.x) GL_STEP(3, ia1.y, ib1.y)
    GL_STEP(4, ia2.x, ib2.x) GL_STEP(5, ia2.y, ib2.y)
    GL_STEP(6, ia3.x, ib3.x) GL_STEP(7, ia3.y, ib3.y)
    GL_STEP(8, ia4.x, ib4.x) GL_STEP(9, ia4.y, ib4.y)
    #undef GL_STEP

    s16x8 so, fo;
    #pragma unroll
    for (int i = 0; i < 8; ++i) { so[i] = (short)f2b(sacc[i]); fo[i] = (short)f2b(facc[i]); }
    *(s16x8*)(SATOM + (size_t)m * H + c8) = so;
    *(s16x8*)(FNEIb + (size_t)m * H + c8) = fo;
}

// ---------------------------------------------------------------------------
// prep_all: block-range-split fusion of prep_w | prep_fbs | cvt_atom | prep_hb
//  [0,320): weights  [320,576): FBS8  [576,3648): atom pad  [3648,11840): HB
// ---------------------------------------------------------------------------
__global__ __launch_bounds__(256) void prep_all(
    const float* __restrict__ Wa, const float* __restrict__ Wna,
    const float* __restrict__ Ws, const float* __restrict__ Wu2,
    const float* __restrict__ bu2, const float* __restrict__ Wu1,
    const float* __restrict__ bu1, const float* __restrict__ bond,
    const int* __restrict__ bg, const int* __restrict__ nn,
    const float* __restrict__ ia, const float* __restrict__ Wnb,
    ushort* __restrict__ WTs, ushort* __restrict__ FBSb,
    ushort* __restrict__ AFin, ushort* __restrict__ HB)
{
    const int bid = blockIdx.x;
    if (bid < 320) {
        // WTa[128][96] | WTna[128][128] | WTslf[128][128] | WTu1f[128][288]
        int t = bid * 256 + threadIdx.x;
        const int tid = t;
        if (t < 128 * 96) { int n = t / 96, k = t % 96;
            WTs[tid] = (k < 82) ? f2b(Wa[k * H + n]) : 0; return; }
        t -= 128 * 96;
        if (t < 128 * 128) { int n = t / 128, k = t % 128;
            WTs[tid] = f2b(Wna[k * H + n]); return; }
        t -= 128 * 128;
        if (t < 128 * 128) { int n = t / 128, k = t % 128;
            WTs[tid] = f2b(Ws[k * H + n]); return; }
        t -= 128 * 128;
        {
            const int n = t / 288, k = t % 288;
            float v = 0.f;
            if (k < 128) {
                v = Wu1[k * H + n];
            } else if (k < 256) {
                const int kk = k - 128;
                float s = 0.f;
                for (int j = 0; j < 128; ++j) s += Wu2[kk * H + j] * Wu1[(128 + j) * H + n];
                v = s;
            } else {
                const int j = k - 256;
                if (j < 6) {
                    float s = 0.f;
                    for (int q = 0; q < 128; ++q) s += Wu2[(128 + j) * H + q] * Wu1[(128 + q) * H + n];
                    v = s;
                } else if (j == 6) {
                    float s = 0.f;
                    for (int q = 0; q < 128; ++q) s += bu2[q] * Wu1[(128 + q) * H + n];
                    v = s;
                } else if (j == 7) {
                    v = bu1[n];
                }
            }
            WTs[tid] = f2b(v);
            return;
        }
    } else if (bid < 576) {
        // FBS8[m][8] = bf16[ sum_nb bond[bg[m,nb]][0..5], num_nbs, 1 ]
        const int m = (bid - 320) * 256 + threadIdx.x;
        const int b = m >> 10;
        const int nnb = nn[m];
        float s[6] = {0,0,0,0,0,0};
        for (int nb = 0; nb < nnb; ++nb) {
            const int ib = bg[m * NB + nb];
            const float* fb = bond + ((size_t)(b << 11) + (size_t)ib) * 6;
            #pragma unroll
            for (int j = 0; j < 6; ++j) s[j] += fb[j];
        }
        s16x8 o;
        #pragma unroll
        for (int j = 0; j < 6; ++j) o[j] = (short)f2b(s[j]);
        o[6] = (short)f2b((float)nnb);
        o[7] = (short)f2b(1.0f);
        *(s16x8*)(FBSb + (size_t)m * 8) = o;
    } else if (bid < 3648) {
        // input_atom [M][82] f32 -> [M][96] bf16 (zero-padded)
        const int tid = (bid - 576) * 256 + threadIdx.x;   // M*12
        const int m = tid / 12, c = (tid % 12) * 8;
        s16x8 v;
        #pragma unroll
        for (int i = 0; i < 8; ++i) {
            const int k = c + i;
            v[i] = (short)(k < 82 ? f2b(ia[(size_t)m * 82 + k]) : 0);
        }
        *(s16x8*)(AFin + (size_t)m * 96 + c) = v;
    } else {
        // HB[b][e][:] = bond[b,e,:] @ W_nei_bond  (bf16)
        const int t = (bid - 3648) * 256 + threadIdx.x;    // B*E*16
        const int r = t >> 4, c8 = (t & 15) * 8;
        const float* fb = bond + (size_t)r * 6;
        const float2 f01 = *(const float2*)fb;
        const float2 f23 = *(const float2*)(fb + 2);
        const float2 f45 = *(const float2*)(fb + 4);
        s16x8 o;
        #pragma unroll
        for (int i = 0; i < 8; ++i) {
            const int c = c8 + i;
            const float v = f01.x * Wnb[0 * H + c] + f01.y * Wnb[1 * H + c]
                          + f23.x * Wnb[2 * H + c] + f23.y * Wnb[3 * H + c]
                          + f45.x * Wnb[4 * H + c] + f45.y * Wnb[5 * H + c];
            o[i] = (short)f2b(v);
        }
        *(s16x8*)(HB + (size_t)r * H + c8) = o;
    }
}

// ---------------------------------------------------------------------------
extern "C" void kernel_launch(void* const* d_in, const int* in_sizes, int n_in,
                              void* d_out, int out_size, void* d_ws, size_t ws_size,
                              hipStream_t stream)
{
    (void)in_sizes; (void)n_in; (void)out_size; (void)ws_size;

    const float* input_atom = (const float*)d_in[0];
    const float* input_bond = (const float*)d_in[1];
    const int*   atom_graph = (const int*)d_in[2];
    const int*   bond_graph = (const int*)d_in[3];
    const int*   num_nbs    = (const int*)d_in[4];
    const float* node_mask  = (const float*)d_in[5];
    const float* W_atom     = (const float*)d_in[6];
    const float* W_nei_atom = (const float*)d_in[7];
    const float* W_nei_bond = (const float*)d_in[8];
    const float* W_self     = (const float*)d_in[9];
    const float* W_U2       = (const float*)d_in[10];
    const float* b_U2       = (const float*)d_in[11];
    const float* W_U1       = (const float*)d_in[12];
    const float* b_U1       = (const float*)d_in[13];

    char* ws = (char*)d_ws;
    const size_t MB = 1024 * 1024;
    ushort* AF0   = (ushort*)(ws);               // [0,16) MB
    ushort* AF1   = (ushort*)(ws + 16 * MB);     // [16,32) MB (FNEI at last depth)
    ushort* SATw  = (ushort*)(ws + 32 * MB);     // [32,48) MB (ATW at last depth)
    ushort* ATW   = SATw;
    ushort* AFin  = (ushort*)(ws + 48 * MB);     // [48,60) MB
    ushort* HB    = (ushort*)(ws + 64 * MB);     // [64,96) MB
    ushort* SATl  = (ushort*)(ws + 96 * MB);     // [96,112) MB
    ushort* FBSb  = (ushort*)(ws + 112 * MB);    // 1 MB
    ushort* WTs_  = (ushort*)(ws + 113 * MB);    // ~160 KB

    ushort* WTa   = WTs_;                        // [128][96]
    ushort* WTna  = WTa   + 128 * 96;            // [128][128]
    ushort* WTslf = WTna  + 128 * 128;           // [128][128]
    ushort* WTu1f = WTslf + 128 * 128;           // [128][288]

    float*  out0  = (float*)d_out;               // kernel [M][128] f32
    float*  out1  = out0 + SL;                   // atom_features [M][128] f32
    ushort* FNEIb = AF1;                         // last-depth FNEI scratch

    prep_all<<<11840, 256, 0, stream>>>(W_atom, W_nei_atom, W_self, W_U2, b_U2,
                                        W_U1, b_U1, input_bond, bond_graph,
                                        num_nbs, input_atom, W_nei_bond,
                                        WTs_, FBSb, AFin, HB);

    // AF0 = input_atom @ W_atom   (K=96 padded)
    gemm_af<3, 0><<<1024, 256, 0, stream>>>(AFin, WTa, nullptr, nullptr,
                                            nullptr, AF0);

    // depth 0
    gather_satom<<<4096, 256, 0, stream>>>(AF0, atom_graph, num_nbs, SATw);
    u1f<false><<<1024, 256, 0, stream>>>(AF0, SATw, FBSb, WTu1f, nullptr, AF1);
    // depth 1
    gather_satom<<<4096, 256, 0, stream>>>(AF1, atom_graph, num_nbs, SATw);
    u1f<false><<<1024, 256, 0, stream>>>(AF1, SATw, FBSb, WTu1f, nullptr, AF0);

    // ---- last depth (AF = AF0; AF1 dead -> FNEI scratch; SATw -> ATW) ----
    gemm_af<4, 0><<<1024, 256, 0, stream>>>(AF0, WTna, nullptr, nullptr,
                                            nullptr, ATW);
    gather_last<<<4096, 256, 0, stream>>>(AF0, ATW, HB, atom_graph, bond_graph,
                                          num_nbs, SATl, FNEIb);
    // atom_features -> out1 (f32)  ||  kernel -> out0 (f32)
    final2<<<2048, 256, 0, stream>>>(AF0, SATl, FBSb, WTu1f, WTslf, FNEIb,
                                     node_mask, out1, out0);
}